// Round 6
// baseline (665.773 us; speedup 1.0000x reference)
//
#include <hip/hip_runtime.h>

// ---------------- problem constants ----------------
#define NB      8
#define SEQ     4096
#define DM      512
#define DFF     2048
#define NE      8
#define NTOK    32768            // NB*SEQ
#define NPB     2097152          // SEQ*DM elems per batch
#define MAXROWS 66560            // 520 * 128 >= 65536 + 8*127
#define MAXTILES 520

// output layout (fp32 elements)
#define OUT_LB   16777216
#define OUT_TOPK 16777217
#define OUT_TASK 16842753

// ws byte offsets
#define WS_BSTATS   0            // double[8][64][2]
#define WS_DMEAN    8192
#define WS_DRSTD    8256
#define WS_DCOLSUM  8320
#define WS_DTASK    8384         // double[8][8]
#define WS_HIST     8896
#define WS_CURSOR   8928
#define WS_SEGOFF   8960
#define WS_HDR_END  9216
#define WS_ROUTE_E  9216         // int2[32768]
#define WS_ROUTE_P  271360       // float2[32768]
#define WS_ATOK     533504       // int[66560]
#define WS_APROB    799744       // float[66560]
#define WS_TOKPOS   1065984      // int[32768*2]
#define WS_W1T      1328128      // ushort[8*2048*512]
#define WS_W2T      18105344     // ushort[8*512*2048]
#define WS_XB       34882560     // ushort[32768*512] (bf16 x copy)
#define WS_Y        68436992     // ushort[66560*512] (per-assignment y, bf16)
#define WS_H        136594432    // ushort[TPC*128*2048] (per-chunk hidden)

typedef __attribute__((ext_vector_type(4))) float  f32x4;
typedef __attribute__((ext_vector_type(8))) __bf16 bf16x8;
typedef __attribute__((ext_vector_type(8))) short  s16x8;

__device__ __forceinline__ unsigned short f2bf(float f) {
    unsigned int u = __builtin_bit_cast(unsigned int, f);
    u += 0x7FFFu + ((u >> 16) & 1u);
    return (unsigned short)(u >> 16);
}
__device__ __forceinline__ float bf2f(unsigned short b) {
    unsigned int u = ((unsigned int)b) << 16;
    return __builtin_bit_cast(float, u);
}
// pack 2 fp32 -> 2 bf16 (RNE, same rounding as f2bf)
__device__ __forceinline__ unsigned int pkbf(float a, float b) {
    unsigned int r;
    asm("v_cvt_pk_bf16_f32 %0, %1, %2" : "=v"(r) : "v"(a), "v"(b));
    return r;
}

// async global->LDS 16B: LDS dest is wave-uniform base (+lane*16 implicit),
// global source is per-lane (carries the XOR swizzle).
#define GLDS16(g, l)                                                              \
    __builtin_amdgcn_global_load_lds(                                             \
        (const __attribute__((address_space(1))) unsigned int*)(const void*)(g),  \
        (__attribute__((address_space(3))) unsigned int*)(void*)(l), 16, 0, 0)

// ---------------- weight transpose + bf16 convert ----------------
// in: fp32 [E][R][C]  ->  out: bf16 bits [E][C][R]
__global__ void k_transpose_bf16(const float* __restrict__ in,
                                 unsigned short* __restrict__ outT,
                                 int R, int C) {
    __shared__ float tile[32][33];
    int e = blockIdx.z;
    const float* src = in + (size_t)e * R * C;
    unsigned short* dst = outT + (size_t)e * R * C;
    int tx = threadIdx.x & 31, ty = threadIdx.x >> 5;
    int c0 = blockIdx.x * 32, r0 = blockIdx.y * 32;
#pragma unroll
    for (int i = 0; i < 4; i++) {
        int r = r0 + ty + i * 8;
        tile[ty + i * 8][tx] = src[(size_t)r * C + c0 + tx];
    }
    __syncthreads();
#pragma unroll
    for (int i = 0; i < 4; i++) {
        int rr = c0 + ty + i * 8;
        dst[(size_t)rr * R + r0 + tx] = f2bf(tile[tx][ty + i * 8]);
    }
}

// ---------------- x -> bf16 copy ----------------
__global__ void k_xbf16(const float* __restrict__ x, unsigned short* __restrict__ xb) {
    size_t i = ((size_t)blockIdx.x * 256 + threadIdx.x) * 8;
    float4 a = *(const float4*)(x + i);
    float4 b = *(const float4*)(x + i + 4);
    s16x8 o = {(short)f2bf(a.x), (short)f2bf(a.y), (short)f2bf(a.z), (short)f2bf(a.w),
               (short)f2bf(b.x), (short)f2bf(b.y), (short)f2bf(b.z), (short)f2bf(b.w)};
    *(s16x8*)(xb + i) = o;
}

// ---------------- batch stats (stage 1): per (batch, chunk) fp64 sums ----------------
__global__ void k_reduce_stats(const float* __restrict__ x, double* __restrict__ bstats) {
    int b = blockIdx.y, c = blockIdx.x, t = threadIdx.x;
    const float* p = x + (size_t)b * NPB + (size_t)c * 32768;
    double s = 0.0, ss = 0.0;
#pragma unroll 4
    for (int i = 0; i < 32; i++) {
        float4 v = *(const float4*)(p + i * 1024 + t * 4);
        s  += (double)v.x + (double)v.y + (double)v.z + (double)v.w;
        ss += (double)v.x * v.x + (double)v.y * v.y + (double)v.z * v.z + (double)v.w * v.w;
    }
    for (int o = 32; o; o >>= 1) { s += __shfl_down(s, o); ss += __shfl_down(ss, o); }
    __shared__ double as_[4], ass_[4];
    int w = t >> 6;
    if ((t & 63) == 0) { as_[w] = s; ass_[w] = ss; }
    __syncthreads();
    if (t == 0) {
        s  = as_[0] + as_[1] + as_[2] + as_[3];
        ss = ass_[0] + ass_[1] + ass_[2] + ass_[3];
        bstats[(b * 64 + c) * 2]     = s;
        bstats[(b * 64 + c) * 2 + 1] = ss;
    }
}

// ---------------- stage 2: finalize mean/rstd, gate colsum, task terms ----------------
__global__ void k_finalize(const double* __restrict__ bstats,
                           double* __restrict__ dmean, double* __restrict__ drstd,
                           double* __restrict__ dcolsum, double* __restrict__ dtask,
                           const float* __restrict__ gw, const float* __restrict__ gb,
                           const float* __restrict__ temb, const int* __restrict__ task_id,
                           float* __restrict__ out_task) {
    int t = threadIdx.x;
    int b = t >> 5, l = t & 31;
    double s  = bstats[(b * 64 + l) * 2]     + bstats[(b * 64 + l + 32) * 2];
    double ss = bstats[(b * 64 + l) * 2 + 1] + bstats[(b * 64 + l + 32) * 2 + 1];
    for (int o = 16; o; o >>= 1) { s += __shfl_down(s, o, 32); ss += __shfl_down(ss, o, 32); }
    if (l == 0) {
        double N = (double)NPB;
        double m = s / N;
        double var = ss / N - m * m;
        dmean[b] = m;
        drstd[b] = 1.0 / sqrt(var + 1e-5);
    }
    // gate_w column sums (rows 0..511)
    __shared__ double colp[32][8];
    {
        int e = t & 7, g = t >> 3;
        double a = 0.0;
        for (int r = g * 16; r < g * 16 + 16; r++) a += (double)gw[r * 8 + e];
        colp[g][e] = a;
    }
    __syncthreads();
    if (t < 8) {
        double a = 0.0;
        for (int g = 0; g < 32; g++) a += colp[g][t];
        dcolsum[t] = a;
    }
    if (t < 64) {
        int b2 = t >> 3, e = t & 7;
        int tid = task_id[b2];
        double a = (double)gb[e];
        for (int d = 0; d < 64; d++)
            a += (double)temb[tid * 64 + d] * (double)gw[(512 + d) * 8 + e];
        dtask[t] = a;
    }
    if (t < 8) out_task[t] = (float)task_id[t];
}

// ---------------- gate: one THREAD per token; LDS reads are pure broadcast ----------------
__global__ void __launch_bounds__(256) k_gate(const float* __restrict__ x,
                                              const float* __restrict__ gw,
                                              const double* __restrict__ dmean,
                                              const double* __restrict__ drstd,
                                              const double* __restrict__ dcolsum,
                                              const double* __restrict__ dtask,
                                              int* __restrict__ hist,
                                              int2* __restrict__ route_e,
                                              float2* __restrict__ route_p,
                                              float* __restrict__ out_topk) {
    __shared__ float gws[DM * 8];    // 16 KB, rows 0..511 of gate_w
    __shared__ int lh[8];
    int t = threadIdx.x;
    if (t < 8) lh[t] = 0;
#pragma unroll
    for (int i = 0; i < 16; i++) gws[i * 256 + t] = gw[i * 256 + t];
    __syncthreads();

    int token = blockIdx.x * 256 + t;
    int b = token >> 12;
    const float4* xp = (const float4*)(x + (size_t)token * DM);

    double acc[8] = {0, 0, 0, 0, 0, 0, 0, 0};
#pragma unroll 2
    for (int i = 0; i < 128; i++) {
        float4 v = xp[i];
        double dx = v.x, dy = v.y, dz = v.z, dw = v.w;
        const float* g = &gws[i * 32];        // wave-uniform -> broadcast, 0 conflicts
#pragma unroll
        for (int e = 0; e < 8; e++)
            acc[e] += dx * (double)g[e] + dy * (double)g[8 + e]
                    + dz * (double)g[16 + e] + dw * (double)g[24 + e];
    }

    double m = dmean[b], rs = drstd[b];
    double lg[8];
#pragma unroll
    for (int e = 0; e < 8; e++) lg[e] = rs * (acc[e] - m * dcolsum[e]) + dtask[b * 8 + e];
    int i0 = 0;
#pragma unroll
    for (int e = 1; e < 8; e++) if (lg[e] > lg[i0]) i0 = e;
    int i1 = (i0 == 0) ? 1 : 0;
#pragma unroll
    for (int e = 0; e < 8; e++) if (e != i0 && lg[e] > lg[i1]) i1 = e;
    double d = exp(lg[i1] - lg[i0]);
    double p0 = 1.0 / (1.0 + d);
    double p1 = d / (1.0 + d);
    out_topk[token * 2]     = (float)i0;
    out_topk[token * 2 + 1] = (float)i1;
    atomicAdd(&lh[i0], 1);
    atomicAdd(&lh[i1], 1);
    route_e[token] = make_int2(i0, i1);
    route_p[token] = make_float2((float)p0, (float)p1);
    __syncthreads();
    if (t < 8) atomicAdd(&hist[t], lh[t]);
}

// ---------------- segment offsets (tile-padded) + lb_loss ----------------
__global__ void k_offsets_lb(const int* __restrict__ hist, int* __restrict__ seg_off,
                             float* __restrict__ out_lb) {
    if (threadIdx.x == 0) {
        int off = 0;
        double ssd = 0.0;
        for (int e = 0; e < 8; e++) {
            seg_off[e] = off;
            off += (hist[e] + 127) & ~127;
            double d = (double)hist[e] - 8192.0;
            ssd += d * d;
        }
        seg_off[8] = off;
        double stdv = sqrt(ssd / 7.0);
        double m = 8192.0 + 1e-6;
        double r = stdv / m;
        *out_lb = (float)(r * r);
    }
}

// ---------------- scatter: LDS-aggregated two-level + inverse map (tokpos) ----------------
__global__ void __launch_bounds__(256) k_scatter(const int2* __restrict__ route_e,
                                                 const float2* __restrict__ route_p,
                                                 const int* __restrict__ seg_off,
                                                 int* __restrict__ cursor,
                                                 int* __restrict__ atok,
                                                 float* __restrict__ aprob,
                                                 int* __restrict__ tokpos) {
    __shared__ int lcount[8];
    __shared__ int lbase[8];
    int t = threadIdx.x;
    if (t < 8) lcount[t] = 0;
    __syncthreads();
    int tok = blockIdx.x * 256 + t;
    int2 e = route_e[tok];
    float2 p = route_p[tok];
    int p0 = atomicAdd(&lcount[e.x], 1);   // LDS atomic: block-local position
    int p1 = atomicAdd(&lcount[e.y], 1);
    __syncthreads();
    if (t < 8) lbase[t] = atomicAdd(&cursor[t], lcount[t]);  // one global atomic per (block, expert)
    __syncthreads();
    int a0 = seg_off[e.x] + lbase[e.x] + p0;
    atok[a0] = tok; aprob[a0] = p.x;
    int a1 = seg_off[e.y] + lbase[e.y] + p1;
    atok[a1] = tok; aprob[a1] = p.y;
    tokpos[tok * 2]     = a0;
    tokpos[tok * 2 + 1] = a1;
}

// ============ MFMA GEMMs: global_load_lds(16B) + XOR-swizzled [128][64] LDS ============
// LDS slot (R, c) holds source k-chunk (c ^ (R&7)); ds_read applies the same XOR.
// MFMA args SWAPPED (mfma(b,a)): lane's 4 acc elems = 4 consecutive OUTPUT COLUMNS
// -> epilogue packs pairs via v_cvt_pk_bf16_f32 and stores 8B per (m,n).

// ---------------- GEMM1: H[chunk] = silu(X_gather @ w1[e] + b1[e]), full DFF ----------------
__global__ void __launch_bounds__(256) k_gemm1(const unsigned short* __restrict__ xb,
                                               const unsigned short* __restrict__ w1t,
                                               const float* __restrict__ b1,
                                               const int* __restrict__ atok,
                                               const int* __restrict__ seg_off,
                                               unsigned short* __restrict__ H,
                                               int t0) {
    int nwg = (int)gridDim.x;                       // TPC*16, multiple of 8
    int bid = (int)blockIdx.x;
    int wg = (bid & 7) * (nwg >> 3) + (bid >> 3);   // XCD-chunked logical id
    int xt = wg >> 4, y = wg & 15;                  // NY = 16
    int r0 = (t0 + xt) * 128;
    if (r0 >= seg_off[8]) return;
    int e = 0;
    while (seg_off[e + 1] <= r0) e++;
    int f0 = y * 128;

    int tid = threadIdx.x;
    int w = tid >> 6, l = tid & 63;
    int c = l & 7;

    __shared__ __align__(16) unsigned short As[128 * 64];
    __shared__ __align__(16) unsigned short Bs[128 * 64];

    const unsigned short* asrc[4];
    const unsigned short* bsrc[4];
    unsigned short*       adst[4];
    unsigned short*       bdst[4];
#pragma unroll
    for (int j = 0; j < 4; j++) {
        int R = w * 32 + j * 8 + (l >> 3);
        int cs = c ^ (R & 7);
        int tok = atok[r0 + R]; if (tok < 0) tok = 0;
        asrc[j] = xb + (size_t)tok * DM + cs * 8;
        bsrc[j] = w1t + ((size_t)e * DFF + f0 + R) * DM + cs * 8;
        adst[j] = &As[(size_t)(w * 32 + j * 8) * 64];
        bdst[j] = &Bs[(size_t)(w * 32 + j * 8) * 64];
    }

    f32x4 acc[4][4] = {};
    int wr = w >> 1, wc = w & 1, lr = l & 15, q = l >> 4;

    for (int k0 = 0; k0 < DM; k0 += 64) {
#pragma unroll
        for (int j = 0; j < 4; j++) {
            GLDS16(asrc[j] + k0, adst[j]);
            GLDS16(bsrc[j] + k0, bdst[j]);
        }
        __syncthreads();
#pragma unroll
        for (int h = 0; h < 2; h++) {
            bf16x8 af[4], bfv[4];
#pragma unroll
            for (int m = 0; m < 4; m++) {
                int R = wr * 64 + m * 16 + lr;
                af[m] = *(const bf16x8*)&As[R * 64 + (((h << 2) + q) ^ (R & 7)) * 8];
            }
#pragma unroll
            for (int n = 0; n < 4; n++) {
                int R = wc * 64 + n * 16 + lr;
                bfv[n] = *(const bf16x8*)&Bs[R * 64 + (((h << 2) + q) ^ (R & 7)) * 8];
            }
#pragma unroll
            for (int m = 0; m < 4; m++)
#pragma unroll
                for (int n = 0; n < 4; n++)
                    acc[m][n] = __builtin_amdgcn_mfma_f32_16x16x32_bf16(bfv[n], af[m], acc[m][n], 0, 0, 0);
        }
        __syncthreads();
    }

    // epilogue: acc[m][n][j] = H[r = wr*64+m*16+lr][f = f0 + wc*64 + n*16 + q*4 + j]
    const float* b1e = b1 + e * DFF + f0;
#pragma unroll
    for (int m = 0; m < 4; m++) {
        int r = wr * 64 + m * 16 + lr;
        unsigned short* hrow = H + ((size_t)xt * 128 + r) * DFF + f0;
#pragma unroll
        for (int n = 0; n < 4; n++) {
            int fc = wc * 64 + n * 16 + q * 4;
            float4 bias = *(const float4*)(b1e + fc);
            float v0 = acc[m][n][0] + bias.x; v0 = v0 / (1.0f + __expf(-v0));
            float v1 = acc[m][n][1] + bias.y; v1 = v1 / (1.0f + __expf(-v1));
            float v2 = acc[m][n][2] + bias.z; v2 = v2 / (1.0f + __expf(-v2));
            float v3 = acc[m][n][3] + bias.w; v3 = v3 / (1.0f + __expf(-v3));
            uint2 pk = make_uint2(pkbf(v0, v1), pkbf(v2, v3));
            *(uint2*)(hrow + fc) = pk;
        }
    }
}

// ---------------- GEMM2: Y[aidx] = H[chunk] @ w2[e]  (K=2048, plain bf16 stores) ----------------
__global__ void __launch_bounds__(256) k_gemm2(const unsigned short* __restrict__ H,
                                               const unsigned short* __restrict__ w2t,
                                               const int* __restrict__ seg_off,
                                               unsigned short* __restrict__ Y,
                                               int t0) {
    int nwg = (int)gridDim.x;                       // TPC*4, TPC even -> %8==0
    int bid = (int)blockIdx.x;
    int wg = (bid & 7) * (nwg >> 3) + (bid >> 3);
    int xt = wg >> 2, y = wg & 3;                   // NY = 4
    int r0 = (t0 + xt) * 128;
    if (r0 >= seg_off[8]) return;
    int e = 0;
    while (seg_off[e + 1] <= r0) e++;
    int d0 = y * 128;

    int tid = threadIdx.x;
    int w = tid >> 6, l = tid & 63;
    int c = l & 7;

    __shared__ __align__(16) unsigned short As[128 * 64];
    __shared__ __align__(16) unsigned short Bs[128 * 64];

    const unsigned short* asrc[4];
    const unsigned short* bsrc[4];
    unsigned short*       adst[4];
    unsigned short*       bdst[4];
#pragma unroll
    for (int j = 0; j < 4; j++) {
        int R = w * 32 + j * 8 + (l >> 3);
        int cs = c ^ (R & 7);
        asrc[j] = H + ((size_t)xt * 128 + R) * DFF + cs * 8;
        bsrc[j] = w2t + ((size_t)e * DM + d0 + R) * DFF + cs * 8;
        adst[j] = &As[(size_t)(w * 32 + j * 8) * 64];
        bdst[j] = &Bs[(size_t)(w * 32 + j * 8) * 64];
    }

    f32x4 acc[4][4] = {};
    int wr = w >> 1, wc = w & 1, lr = l & 15, q = l >> 4;

    for (int k0 = 0; k0 < DFF; k0 += 64) {          // 32 K-iters
#pragma unroll
        for (int j = 0; j < 4; j++) {
            GLDS16(asrc[j] + k0, adst[j]);
            GLDS16(bsrc[j] + k0, bdst[j]);
        }
        __syncthreads();
#pragma unroll
        for (int h = 0; h < 2; h++) {
            bf16x8 af[4], bfv[4];
#pragma unroll
            for (int m = 0; m < 4; m++) {
                int R = wr * 64 + m * 16 + lr;
                af[m] = *(const bf16x8*)&As[R * 64 + (((h << 2) + q) ^ (R & 7)) * 8];
            }
#pragma unroll
            for (int n = 0; n < 4; n++) {
                int R = wc * 64 + n * 16 + lr;
                bfv[n] = *(const bf16x8*)&Bs[R * 64 + (((h << 2) + q) ^ (R & 7)) * 8];
            }
#pragma unroll
            for (int m = 0; m < 4; m++)
#pragma unroll
                for (int n = 0; n < 4; n++)
                    acc[m][n] = __builtin_amdgcn_mfma_f32_16x16x32_bf16(bfv[n], af[m], acc[m][n], 0, 0, 0);
        }
        __syncthreads();
    }

    // epilogue: acc[m][n][j] = Y[r = wr*64+m*16+lr][d = d0 + wc*64 + n*16 + q*4 + j]
#pragma unroll
    for (int m = 0; m < 4; m++) {
        int r = wr * 64 + m * 16 + lr;
        unsigned short* yrow = Y + (size_t)(r0 + r) * DM + d0;
#pragma unroll
        for (int n = 0; n < 4; n++) {
            int dc = wc * 64 + n * 16 + q * 4;
            uint2 pk = make_uint2(pkbf(acc[m][n][0], acc[m][n][1]),
                                  pkbf(acc[m][n][2], acc[m][n][3]));
            *(uint2*)(yrow + dc) = pk;
        }
    }
}

// ---------------- combine: out[t] = p0*(Y[a0]+b2[e0]) + p1*(Y[a1]+b2[e1]) ----------------
__global__ void __launch_bounds__(256) k_combine(const unsigned short* __restrict__ Y,
                                                 const float* __restrict__ b2,
                                                 const int* __restrict__ tokpos,
                                                 const int2* __restrict__ route_e,
                                                 const float2* __restrict__ route_p,
                                                 float* __restrict__ out) {
    int gt = blockIdx.x * 256 + threadIdx.x;
    int token = gt >> 6;                  // 64 threads per token
    int cbase = (gt & 63) * 8;
    int2 e = route_e[token];
    float2 p = route_p[token];
    int a0 = tokpos[token * 2], a1 = tokpos[token * 2 + 1];
    s16x8 y0 = *(const s16x8*)(Y + (size_t)a0 * DM + cbase);
    s16x8 y1 = *(const s16x8*)(Y + (size_t)a1 * DM + cbase);
    const float4* bb0 = (const float4*)(b2 + e.x * DM + cbase);
    const float4* bb1 = (const float4*)(b2 + e.y * DM + cbase);
    float4 b00 = bb0[0], b01 = bb0[1];
    float4 b10 = bb1[0], b11 = bb1[1];
    float r[8];
    r[0] = p.x * (bf2f((unsigned short)y0[0]) + b00.x) + p.y * (bf2f((unsigned short)y1[0]) + b10.x);
    r[1] = p.x * (bf2f((unsigned short)y0[1]) + b00.y) + p.y * (bf2f((unsigned short)y1[1]) + b10.y);
    r[2] = p.x * (bf2f((unsigned short)y0[2]) + b00.z) + p.y * (bf2f((unsigned short)y1[2]) + b10.z);
    r[3] = p.x * (bf2f((unsigned short)y0[3]) + b00.w) + p.y * (bf2f((unsigned short)y1[3]) + b10.w);
    r[4] = p.x * (bf2f((unsigned short)y0[4]) + b01.x) + p.y * (bf2f((unsigned short)y1[4]) + b11.x);
    r[5] = p.x * (bf2f((unsigned short)y0[5]) + b01.y) + p.y * (bf2f((unsigned short)y1[5]) + b11.y);
    r[6] = p.x * (bf2f((unsigned short)y0[6]) + b01.z) + p.y * (bf2f((unsigned short)y1[6]) + b11.z);
    r[7] = p.x * (bf2f((unsigned short)y0[7]) + b01.w) + p.y * (bf2f((unsigned short)y1[7]) + b11.w);
    float* op = out + (size_t)token * DM + cbase;
    *(float4*)op       = make_float4(r[0], r[1], r[2], r[3]);
    *(float4*)(op + 4) = make_float4(r[4], r[5], r[6], r[7]);
}

// ---------------- launch ----------------
extern "C" void kernel_launch(void* const* d_in, const int* in_sizes, int n_in,
                              void* d_out, int out_size, void* d_ws, size_t ws_size,
                              hipStream_t stream) {
    const float* x       = (const float*)d_in[0];
    const int*   task_id = (const int*)d_in[1];
    const float* w1      = (const float*)d_in[2];
    const float* b1      = (const float*)d_in[3];
    const float* w2      = (const float*)d_in[4];
    const float* b2      = (const float*)d_in[5];
    const float* temb    = (const float*)d_in[6];
    const float* gw      = (const float*)d_in[7];
    const float* gb      = (const float*)d_in[8];
    float* out = (float*)d_out;

    char* ws = (char*)d_ws;
    double* bstats   = (double*)(ws + WS_BSTATS);
    double* dmean    = (double*)(ws + WS_DMEAN);
    double* drstd    = (double*)(ws + WS_DRSTD);
    double* dcolsum  = (double*)(ws + WS_DCOLSUM);
    double* dtask    = (double*)(ws + WS_DTASK);
    int*    hist     = (int*)(ws + WS_HIST);
    int*    cursor   = (int*)(ws + WS_CURSOR);
    int*    seg_off  = (int*)(ws + WS_SEGOFF);
    int2*   route_e  = (int2*)(ws + WS_ROUTE_E);
    float2* route_p  = (float2*)(ws + WS_ROUTE_P);
    int*    atok     = (int*)(ws + WS_ATOK);
    float*  aprob    = (float*)(ws + WS_APROB);
    int*    tokpos   = (int*)(ws + WS_TOKPOS);
    unsigned short* w1t = (unsigned short*)(ws + WS_W1T);
    unsigned short* w2t = (unsigned short*)(ws + WS_W2T);
    unsigned short* xb  = (unsigned short*)(ws + WS_XB);
    unsigned short* Y   = (unsigned short*)(ws + WS_Y);
    unsigned short* H   = (unsigned short*)(ws + WS_H);

    // M-chunk size (tiles): fit ws AND keep H chunk Infinity-Cache-resident (<=130 tiles = 68 MB)
    int TPC = (int)((ws_size - (size_t)WS_H) / (size_t)(128 * DFF * 2));
    if (TPC > 130) TPC = 130;
    TPC &= ~1;
    if (TPC < 2) TPC = 2;

    // ws header zero; -1 fill assignment list (pad rows). (d_out final region fully
    // written by k_combine; lb/topk/task by their kernels -> no d_out memset needed)
    hipMemsetAsync(ws, 0, WS_HDR_END, stream);
    hipMemsetAsync(ws + WS_ATOK, 0xFF, (size_t)MAXROWS * sizeof(int), stream);

    // weight transpose + bf16 convert + x copy
    k_transpose_bf16<<<dim3(DFF / 32, DM / 32, NE), 256, 0, stream>>>(w1, w1t, DM, DFF);
    k_transpose_bf16<<<dim3(DM / 32, DFF / 32, NE), 256, 0, stream>>>(w2, w2t, DFF, DM);
    k_xbf16<<<NTOK * DM / 8 / 256, 256, 0, stream>>>(x, xb);

    // layernorm stats
    k_reduce_stats<<<dim3(64, NB), 256, 0, stream>>>(x, bstats);
    k_finalize<<<1, 256, 0, stream>>>(bstats, dmean, drstd, dcolsum, dtask,
                                      gw, gb, temb, task_id, out + OUT_TASK);

    // gate + routing
    k_gate<<<NTOK / 256, 256, 0, stream>>>(x, gw, dmean, drstd, dcolsum, dtask,
                                           hist, route_e, route_p, out + OUT_TOPK);
    k_offsets_lb<<<1, 64, 0, stream>>>(hist, seg_off, out + OUT_LB);
    k_scatter<<<NTOK / 256, 256, 0, stream>>>(route_e, route_p, seg_off, cursor,
                                              atok, aprob, tokpos);

    // expert GEMMs, chunked over assignment rows
    for (int t0 = 0; t0 < MAXTILES; t0 += TPC) {
        k_gemm1<<<TPC * 16, 256, 0, stream>>>(xb, w1t, b1, atok, seg_off, H, t0);
        k_gemm2<<<TPC * 4, 256, 0, stream>>>(H, w2t, seg_off, Y, t0);
    }
    k_combine<<<NTOK / 4, 256, 0, stream>>>(Y, b2, tokpos, route_e, route_p, out);
}

// Round 7
// 642.403 us; speedup vs baseline: 1.0364x; 1.0364x over previous
//
#include <hip/hip_runtime.h>

// ---------------- problem constants ----------------
#define NB      8
#define SEQ     4096
#define DM      512
#define DFF     2048
#define NE      8
#define NTOK    32768            // NB*SEQ
#define NPB     2097152          // SEQ*DM elems per batch
#define MAXROWS 66560            // 520 * 128 >= 65536 + 8*127
#define MAXTILES 520

// output layout (fp32 elements)
#define OUT_LB   16777216
#define OUT_TOPK 16777217
#define OUT_TASK 16842753

// ws byte offsets
#define WS_BSTATS   0            // double[8][64][2]
#define WS_DMEAN    8192
#define WS_DRSTD    8256
#define WS_DCOLSUM  8320
#define WS_DTASK    8384         // double[8][8]
#define WS_HIST     8896
#define WS_CURSOR   8928
#define WS_SEGOFF   8960
#define WS_HDR_END  9216
#define WS_ROUTE_E  9216         // int2[32768]
#define WS_ROUTE_P  271360       // float2[32768]
#define WS_ATOK     533504       // int[66560]
#define WS_APROB    799744       // float[66560]
#define WS_TOKPOS   1065984      // int[32768*2]
#define WS_W1T      1328128      // ushort[8*2048*512]
#define WS_W2T      18105344     // ushort[8*512*2048]
#define WS_XB       34882560     // ushort[32768*512] (bf16 x copy)
#define WS_Y        68436992     // ushort[66560*512] (per-assignment y, bf16)
#define WS_H        136594432    // ushort[TPC*128*2048] (per-chunk hidden)

typedef __attribute__((ext_vector_type(4))) float  f32x4;
typedef __attribute__((ext_vector_type(8))) __bf16 bf16x8;
typedef __attribute__((ext_vector_type(8))) short  s16x8;

__device__ __forceinline__ unsigned short f2bf(float f) {
    unsigned int u = __builtin_bit_cast(unsigned int, f);
    u += 0x7FFFu + ((u >> 16) & 1u);
    return (unsigned short)(u >> 16);
}
__device__ __forceinline__ float bf2f(unsigned short b) {
    unsigned int u = ((unsigned int)b) << 16;
    return __builtin_bit_cast(float, u);
}
// pack 2 fp32 -> 2 bf16 (RNE, same rounding as f2bf)
__device__ __forceinline__ unsigned int pkbf(float a, float b) {
    unsigned int r;
    asm("v_cvt_pk_bf16_f32 %0, %1, %2" : "=v"(r) : "v"(a), "v"(b));
    return r;
}

// async global->LDS 16B: LDS dest is wave-uniform base (+lane*16 implicit),
// global source is per-lane (carries the XOR swizzle).
#define GLDS16(g, l)                                                              \
    __builtin_amdgcn_global_load_lds(                                             \
        (const __attribute__((address_space(1))) unsigned int*)(const void*)(g),  \
        (__attribute__((address_space(3))) unsigned int*)(void*)(l), 16, 0, 0)

// ---------------- weight transpose + bf16 convert ----------------
// in: fp32 [E][R][C]  ->  out: bf16 bits [E][C][R]
__global__ void k_transpose_bf16(const float* __restrict__ in,
                                 unsigned short* __restrict__ outT,
                                 int R, int C) {
    __shared__ float tile[32][33];
    int e = blockIdx.z;
    const float* src = in + (size_t)e * R * C;
    unsigned short* dst = outT + (size_t)e * R * C;
    int tx = threadIdx.x & 31, ty = threadIdx.x >> 5;
    int c0 = blockIdx.x * 32, r0 = blockIdx.y * 32;
#pragma unroll
    for (int i = 0; i < 4; i++) {
        int r = r0 + ty + i * 8;
        tile[ty + i * 8][tx] = src[(size_t)r * C + c0 + tx];
    }
    __syncthreads();
#pragma unroll
    for (int i = 0; i < 4; i++) {
        int rr = c0 + ty + i * 8;
        dst[(size_t)rr * R + r0 + tx] = f2bf(tile[tx][ty + i * 8]);
    }
}

// ---------------- x -> bf16 copy ----------------
__global__ void k_xbf16(const float* __restrict__ x, unsigned short* __restrict__ xb) {
    size_t i = ((size_t)blockIdx.x * 256 + threadIdx.x) * 8;
    float4 a = *(const float4*)(x + i);
    float4 b = *(const float4*)(x + i + 4);
    s16x8 o = {(short)f2bf(a.x), (short)f2bf(a.y), (short)f2bf(a.z), (short)f2bf(a.w),
               (short)f2bf(b.x), (short)f2bf(b.y), (short)f2bf(b.z), (short)f2bf(b.w)};
    *(s16x8*)(xb + i) = o;
}

// ---------------- batch stats (stage 1): per (batch, chunk) fp64 sums ----------------
__global__ void k_reduce_stats(const float* __restrict__ x, double* __restrict__ bstats) {
    int b = blockIdx.y, c = blockIdx.x, t = threadIdx.x;
    const float* p = x + (size_t)b * NPB + (size_t)c * 32768;
    double s = 0.0, ss = 0.0;
#pragma unroll 4
    for (int i = 0; i < 32; i++) {
        float4 v = *(const float4*)(p + i * 1024 + t * 4);
        s  += (double)v.x + (double)v.y + (double)v.z + (double)v.w;
        ss += (double)v.x * v.x + (double)v.y * v.y + (double)v.z * v.z + (double)v.w * v.w;
    }
    for (int o = 32; o; o >>= 1) { s += __shfl_down(s, o); ss += __shfl_down(ss, o); }
    __shared__ double as_[4], ass_[4];
    int w = t >> 6;
    if ((t & 63) == 0) { as_[w] = s; ass_[w] = ss; }
    __syncthreads();
    if (t == 0) {
        s  = as_[0] + as_[1] + as_[2] + as_[3];
        ss = ass_[0] + ass_[1] + ass_[2] + ass_[3];
        bstats[(b * 64 + c) * 2]     = s;
        bstats[(b * 64 + c) * 2 + 1] = ss;
    }
}

// ---------------- stage 2: finalize mean/rstd, gate colsum, task terms ----------------
__global__ void k_finalize(const double* __restrict__ bstats,
                           double* __restrict__ dmean, double* __restrict__ drstd,
                           double* __restrict__ dcolsum, double* __restrict__ dtask,
                           const float* __restrict__ gw, const float* __restrict__ gb,
                           const float* __restrict__ temb, const int* __restrict__ task_id,
                           float* __restrict__ out_task) {
    int t = threadIdx.x;
    int b = t >> 5, l = t & 31;
    double s  = bstats[(b * 64 + l) * 2]     + bstats[(b * 64 + l + 32) * 2];
    double ss = bstats[(b * 64 + l) * 2 + 1] + bstats[(b * 64 + l + 32) * 2 + 1];
    for (int o = 16; o; o >>= 1) { s += __shfl_down(s, o, 32); ss += __shfl_down(ss, o, 32); }
    if (l == 0) {
        double N = (double)NPB;
        double m = s / N;
        double var = ss / N - m * m;
        dmean[b] = m;
        drstd[b] = 1.0 / sqrt(var + 1e-5);
    }
    // gate_w column sums (rows 0..511)
    __shared__ double colp[32][8];
    {
        int e = t & 7, g = t >> 3;
        double a = 0.0;
        for (int r = g * 16; r < g * 16 + 16; r++) a += (double)gw[r * 8 + e];
        colp[g][e] = a;
    }
    __syncthreads();
    if (t < 8) {
        double a = 0.0;
        for (int g = 0; g < 32; g++) a += colp[g][t];
        dcolsum[t] = a;
    }
    if (t < 64) {
        int b2 = t >> 3, e = t & 7;
        int tid = task_id[b2];
        double a = (double)gb[e];
        for (int d = 0; d < 64; d++)
            a += (double)temb[tid * 64 + d] * (double)gw[(512 + d) * 8 + e];
        dtask[t] = a;
    }
    if (t < 8) out_task[t] = (float)task_id[t];
}

// ---------------- gate: one THREAD per token; LDS reads are pure broadcast ----------------
__global__ void __launch_bounds__(256) k_gate(const float* __restrict__ x,
                                              const float* __restrict__ gw,
                                              const double* __restrict__ dmean,
                                              const double* __restrict__ drstd,
                                              const double* __restrict__ dcolsum,
                                              const double* __restrict__ dtask,
                                              int* __restrict__ hist,
                                              int2* __restrict__ route_e,
                                              float2* __restrict__ route_p,
                                              float* __restrict__ out_topk) {
    __shared__ float gws[DM * 8];    // 16 KB, rows 0..511 of gate_w
    __shared__ int lh[8];
    int t = threadIdx.x;
    if (t < 8) lh[t] = 0;
#pragma unroll
    for (int i = 0; i < 16; i++) gws[i * 256 + t] = gw[i * 256 + t];
    __syncthreads();

    int token = blockIdx.x * 256 + t;
    int b = token >> 12;
    const float4* xp = (const float4*)(x + (size_t)token * DM);

    double acc[8] = {0, 0, 0, 0, 0, 0, 0, 0};
#pragma unroll 2
    for (int i = 0; i < 128; i++) {
        float4 v = xp[i];
        double dx = v.x, dy = v.y, dz = v.z, dw = v.w;
        const float* g = &gws[i * 32];        // wave-uniform -> broadcast, 0 conflicts
#pragma unroll
        for (int e = 0; e < 8; e++)
            acc[e] += dx * (double)g[e] + dy * (double)g[8 + e]
                    + dz * (double)g[16 + e] + dw * (double)g[24 + e];
    }

    double m = dmean[b], rs = drstd[b];
    double lg[8];
#pragma unroll
    for (int e = 0; e < 8; e++) lg[e] = rs * (acc[e] - m * dcolsum[e]) + dtask[b * 8 + e];
    int i0 = 0;
#pragma unroll
    for (int e = 1; e < 8; e++) if (lg[e] > lg[i0]) i0 = e;
    int i1 = (i0 == 0) ? 1 : 0;
#pragma unroll
    for (int e = 0; e < 8; e++) if (e != i0 && lg[e] > lg[i1]) i1 = e;
    double d = exp(lg[i1] - lg[i0]);
    double p0 = 1.0 / (1.0 + d);
    double p1 = d / (1.0 + d);
    out_topk[token * 2]     = (float)i0;
    out_topk[token * 2 + 1] = (float)i1;
    atomicAdd(&lh[i0], 1);
    atomicAdd(&lh[i1], 1);
    route_e[token] = make_int2(i0, i1);
    route_p[token] = make_float2((float)p0, (float)p1);
    __syncthreads();
    if (t < 8) atomicAdd(&hist[t], lh[t]);
}

// ---------------- segment offsets (tile-padded) + lb_loss ----------------
__global__ void k_offsets_lb(const int* __restrict__ hist, int* __restrict__ seg_off,
                             float* __restrict__ out_lb) {
    if (threadIdx.x == 0) {
        int off = 0;
        double ssd = 0.0;
        for (int e = 0; e < 8; e++) {
            seg_off[e] = off;
            off += (hist[e] + 127) & ~127;
            double d = (double)hist[e] - 8192.0;
            ssd += d * d;
        }
        seg_off[8] = off;
        double stdv = sqrt(ssd / 7.0);
        double m = 8192.0 + 1e-6;
        double r = stdv / m;
        *out_lb = (float)(r * r);
    }
}

// ---------------- scatter: LDS-aggregated two-level + inverse map (tokpos) ----------------
__global__ void __launch_bounds__(256) k_scatter(const int2* __restrict__ route_e,
                                                 const float2* __restrict__ route_p,
                                                 const int* __restrict__ seg_off,
                                                 int* __restrict__ cursor,
                                                 int* __restrict__ atok,
                                                 float* __restrict__ aprob,
                                                 int* __restrict__ tokpos) {
    __shared__ int lcount[8];
    __shared__ int lbase[8];
    int t = threadIdx.x;
    if (t < 8) lcount[t] = 0;
    __syncthreads();
    int tok = blockIdx.x * 256 + t;
    int2 e = route_e[tok];
    float2 p = route_p[tok];
    int p0 = atomicAdd(&lcount[e.x], 1);   // LDS atomic: block-local position
    int p1 = atomicAdd(&lcount[e.y], 1);
    __syncthreads();
    if (t < 8) lbase[t] = atomicAdd(&cursor[t], lcount[t]);  // one global atomic per (block, expert)
    __syncthreads();
    int a0 = seg_off[e.x] + lbase[e.x] + p0;
    atok[a0] = tok; aprob[a0] = p.x;
    int a1 = seg_off[e.y] + lbase[e.y] + p1;
    atok[a1] = tok; aprob[a1] = p.y;
    tokpos[tok * 2]     = a0;
    tokpos[tok * 2 + 1] = a1;
}

// ============ MFMA GEMMs: 2-phase double-buffered pipeline ============
// LDS: As[2]/Bs[2], XOR-swizzled [128][64] tiles staged via global_load_lds(16B).
// Per iter: issue next-tile stage -> s_waitcnt vmcnt(8) (counted; prefetch stays
// in flight) -> s_barrier -> ds_read+MFMA (setprio 1) -> s_barrier -> flip.
// MFMA args SWAPPED (mfma(b,a)): lane's 4 acc elems = 4 consecutive OUTPUT COLUMNS.

// ---------------- GEMM1: H[chunk] = silu(X_gather @ w1[e] + b1[e]), full DFF ----------------
__global__ void __launch_bounds__(256) k_gemm1(const unsigned short* __restrict__ xb,
                                               const unsigned short* __restrict__ w1t,
                                               const float* __restrict__ b1,
                                               const int* __restrict__ atok,
                                               const int* __restrict__ seg_off,
                                               unsigned short* __restrict__ H,
                                               int t0) {
    int nwg = (int)gridDim.x;                       // TPC*16, multiple of 8
    int bid = (int)blockIdx.x;
    int wg = (bid & 7) * (nwg >> 3) + (bid >> 3);   // XCD-chunked logical id
    int xt = wg >> 4, y = wg & 15;                  // NY = 16
    int r0 = (t0 + xt) * 128;
    if (r0 >= seg_off[8]) return;
    int e = 0;
    while (seg_off[e + 1] <= r0) e++;
    int f0 = y * 128;

    int tid = threadIdx.x;
    int w = tid >> 6, l = tid & 63;
    int c = l & 7;

    __shared__ __align__(16) unsigned short As[2][128 * 64];
    __shared__ __align__(16) unsigned short Bs[2][128 * 64];

    const unsigned short* asrc[4];
    const unsigned short* bsrc[4];
    unsigned short*       adst[4];
    unsigned short*       bdst[4];
#pragma unroll
    for (int j = 0; j < 4; j++) {
        int R = w * 32 + j * 8 + (l >> 3);
        int cs = c ^ (R & 7);
        int tok = atok[r0 + R]; if (tok < 0) tok = 0;
        asrc[j] = xb + (size_t)tok * DM + cs * 8;
        bsrc[j] = w1t + ((size_t)e * DFF + f0 + R) * DM + cs * 8;
        adst[j] = &As[0][(size_t)(w * 32 + j * 8) * 64];
        bdst[j] = &Bs[0][(size_t)(w * 32 + j * 8) * 64];
    }

    f32x4 acc[4][4] = {};
    int wr = w >> 1, wc = w & 1, lr = l & 15, q = l >> 4;

    // prologue: stage k-step 0 into buffer 0
#pragma unroll
    for (int j = 0; j < 4; j++) { GLDS16(asrc[j], adst[j]); GLDS16(bsrc[j], bdst[j]); }

    int cur = 0;
    for (int it = 0; it < DM / 64; ++it) {          // 8 K-steps
        if (it + 1 < DM / 64) {
            int kn = (it + 1) * 64;
            int off = (cur ^ 1) * 128 * 64;
#pragma unroll
            for (int j = 0; j < 4; j++) {
                GLDS16(asrc[j] + kn, adst[j] + off);
                GLDS16(bsrc[j] + kn, bdst[j] + off);
            }
            asm volatile("s_waitcnt vmcnt(8)" ::: "memory");
        } else {
            asm volatile("s_waitcnt vmcnt(0)" ::: "memory");
        }
        __builtin_amdgcn_s_barrier();
        __builtin_amdgcn_sched_barrier(0);
        __builtin_amdgcn_s_setprio(1);
        const unsigned short* Ab = &As[cur][0];
        const unsigned short* Bb = &Bs[cur][0];
#pragma unroll
        for (int h = 0; h < 2; h++) {
            bf16x8 af[4], bfv[4];
#pragma unroll
            for (int m = 0; m < 4; m++) {
                int R = wr * 64 + m * 16 + lr;
                af[m] = *(const bf16x8*)&Ab[R * 64 + (((h << 2) + q) ^ (R & 7)) * 8];
            }
#pragma unroll
            for (int n = 0; n < 4; n++) {
                int R = wc * 64 + n * 16 + lr;
                bfv[n] = *(const bf16x8*)&Bb[R * 64 + (((h << 2) + q) ^ (R & 7)) * 8];
            }
#pragma unroll
            for (int m = 0; m < 4; m++)
#pragma unroll
                for (int n = 0; n < 4; n++)
                    acc[m][n] = __builtin_amdgcn_mfma_f32_16x16x32_bf16(bfv[n], af[m], acc[m][n], 0, 0, 0);
        }
        __builtin_amdgcn_s_setprio(0);
        __builtin_amdgcn_sched_barrier(0);
        asm volatile("" ::: "memory");
        __builtin_amdgcn_s_barrier();
        cur ^= 1;
    }

    // epilogue: acc[m][n][j] = H[r = wr*64+m*16+lr][f = f0 + wc*64 + n*16 + q*4 + j]
    const float* b1e = b1 + e * DFF + f0;
#pragma unroll
    for (int m = 0; m < 4; m++) {
        int r = wr * 64 + m * 16 + lr;
        unsigned short* hrow = H + ((size_t)xt * 128 + r) * DFF + f0;
#pragma unroll
        for (int n = 0; n < 4; n++) {
            int fc = wc * 64 + n * 16 + q * 4;
            float4 bias = *(const float4*)(b1e + fc);
            float v0 = acc[m][n][0] + bias.x; v0 = v0 / (1.0f + __expf(-v0));
            float v1 = acc[m][n][1] + bias.y; v1 = v1 / (1.0f + __expf(-v1));
            float v2 = acc[m][n][2] + bias.z; v2 = v2 / (1.0f + __expf(-v2));
            float v3 = acc[m][n][3] + bias.w; v3 = v3 / (1.0f + __expf(-v3));
            uint2 pk = make_uint2(pkbf(v0, v1), pkbf(v2, v3));
            *(uint2*)(hrow + fc) = pk;
        }
    }
}

// ---------------- GEMM2: Y[aidx] = H[chunk] @ w2[e]  (K=2048, plain bf16 stores) ----------------
__global__ void __launch_bounds__(256) k_gemm2(const unsigned short* __restrict__ H,
                                               const unsigned short* __restrict__ w2t,
                                               const int* __restrict__ seg_off,
                                               unsigned short* __restrict__ Y,
                                               int t0) {
    int nwg = (int)gridDim.x;                       // TPC*4, TPC even -> %8==0
    int bid = (int)blockIdx.x;
    int wg = (bid & 7) * (nwg >> 3) + (bid >> 3);
    int xt = wg >> 2, y = wg & 3;                   // NY = 4
    int r0 = (t0 + xt) * 128;
    if (r0 >= seg_off[8]) return;
    int e = 0;
    while (seg_off[e + 1] <= r0) e++;
    int d0 = y * 128;

    int tid = threadIdx.x;
    int w = tid >> 6, l = tid & 63;
    int c = l & 7;

    __shared__ __align__(16) unsigned short As[2][128 * 64];
    __shared__ __align__(16) unsigned short Bs[2][128 * 64];

    const unsigned short* asrc[4];
    const unsigned short* bsrc[4];
    unsigned short*       adst[4];
    unsigned short*       bdst[4];
#pragma unroll
    for (int j = 0; j < 4; j++) {
        int R = w * 32 + j * 8 + (l >> 3);
        int cs = c ^ (R & 7);
        asrc[j] = H + ((size_t)xt * 128 + R) * DFF + cs * 8;
        bsrc[j] = w2t + ((size_t)e * DM + d0 + R) * DFF + cs * 8;
        adst[j] = &As[0][(size_t)(w * 32 + j * 8) * 64];
        bdst[j] = &Bs[0][(size_t)(w * 32 + j * 8) * 64];
    }

    f32x4 acc[4][4] = {};
    int wr = w >> 1, wc = w & 1, lr = l & 15, q = l >> 4;

    // prologue
#pragma unroll
    for (int j = 0; j < 4; j++) { GLDS16(asrc[j], adst[j]); GLDS16(bsrc[j], bdst[j]); }

    int cur = 0;
    for (int it = 0; it < DFF / 64; ++it) {         // 32 K-steps
        if (it + 1 < DFF / 64) {
            int kn = (it + 1) * 64;
            int off = (cur ^ 1) * 128 * 64;
#pragma unroll
            for (int j = 0; j < 4; j++) {
                GLDS16(asrc[j] + kn, adst[j] + off);
                GLDS16(bsrc[j] + kn, bdst[j] + off);
            }
            asm volatile("s_waitcnt vmcnt(8)" ::: "memory");
        } else {
            asm volatile("s_waitcnt vmcnt(0)" ::: "memory");
        }
        __builtin_amdgcn_s_barrier();
        __builtin_amdgcn_sched_barrier(0);
        __builtin_amdgcn_s_setprio(1);
        const unsigned short* Ab = &As[cur][0];
        const unsigned short* Bb = &Bs[cur][0];
#pragma unroll
        for (int h = 0; h < 2; h++) {
            bf16x8 af[4], bfv[4];
#pragma unroll
            for (int m = 0; m < 4; m++) {
                int R = wr * 64 + m * 16 + lr;
                af[m] = *(const bf16x8*)&Ab[R * 64 + (((h << 2) + q) ^ (R & 7)) * 8];
            }
#pragma unroll
            for (int n = 0; n < 4; n++) {
                int R = wc * 64 + n * 16 + lr;
                bfv[n] = *(const bf16x8*)&Bb[R * 64 + (((h << 2) + q) ^ (R & 7)) * 8];
            }
#pragma unroll
            for (int m = 0; m < 4; m++)
#pragma unroll
                for (int n = 0; n < 4; n++)
                    acc[m][n] = __builtin_amdgcn_mfma_f32_16x16x32_bf16(bfv[n], af[m], acc[m][n], 0, 0, 0);
        }
        __builtin_amdgcn_s_setprio(0);
        __builtin_amdgcn_sched_barrier(0);
        asm volatile("" ::: "memory");
        __builtin_amdgcn_s_barrier();
        cur ^= 1;
    }

    // epilogue: acc[m][n][j] = Y[r = wr*64+m*16+lr][d = d0 + wc*64 + n*16 + q*4 + j]
#pragma unroll
    for (int m = 0; m < 4; m++) {
        int r = wr * 64 + m * 16 + lr;
        unsigned short* yrow = Y + (size_t)(r0 + r) * DM + d0;
#pragma unroll
        for (int n = 0; n < 4; n++) {
            int dc = wc * 64 + n * 16 + q * 4;
            uint2 pk = make_uint2(pkbf(acc[m][n][0], acc[m][n][1]),
                                  pkbf(acc[m][n][2], acc[m][n][3]));
            *(uint2*)(yrow + dc) = pk;
        }
    }
}

// ---------------- combine: out[t] = p0*(Y[a0]+b2[e0]) + p1*(Y[a1]+b2[e1]) ----------------
__global__ void __launch_bounds__(256) k_combine(const unsigned short* __restrict__ Y,
                                                 const float* __restrict__ b2,
                                                 const int* __restrict__ tokpos,
                                                 const int2* __restrict__ route_e,
                                                 const float2* __restrict__ route_p,
                                                 float* __restrict__ out) {
    int gt = blockIdx.x * 256 + threadIdx.x;
    int token = gt >> 6;                  // 64 threads per token
    int cbase = (gt & 63) * 8;
    int2 e = route_e[token];
    float2 p = route_p[token];
    int a0 = tokpos[token * 2], a1 = tokpos[token * 2 + 1];
    s16x8 y0 = *(const s16x8*)(Y + (size_t)a0 * DM + cbase);
    s16x8 y1 = *(const s16x8*)(Y + (size_t)a1 * DM + cbase);
    const float4* bb0 = (const float4*)(b2 + e.x * DM + cbase);
    const float4* bb1 = (const float4*)(b2 + e.y * DM + cbase);
    float4 b00 = bb0[0], b01 = bb0[1];
    float4 b10 = bb1[0], b11 = bb1[1];
    float r[8];
    r[0] = p.x * (bf2f((unsigned short)y0[0]) + b00.x) + p.y * (bf2f((unsigned short)y1[0]) + b10.x);
    r[1] = p.x * (bf2f((unsigned short)y0[1]) + b00.y) + p.y * (bf2f((unsigned short)y1[1]) + b10.y);
    r[2] = p.x * (bf2f((unsigned short)y0[2]) + b00.z) + p.y * (bf2f((unsigned short)y1[2]) + b10.z);
    r[3] = p.x * (bf2f((unsigned short)y0[3]) + b00.w) + p.y * (bf2f((unsigned short)y1[3]) + b10.w);
    r[4] = p.x * (bf2f((unsigned short)y0[4]) + b01.x) + p.y * (bf2f((unsigned short)y1[4]) + b11.x);
    r[5] = p.x * (bf2f((unsigned short)y0[5]) + b01.y) + p.y * (bf2f((unsigned short)y1[5]) + b11.y);
    r[6] = p.x * (bf2f((unsigned short)y0[6]) + b01.z) + p.y * (bf2f((unsigned short)y1[6]) + b11.z);
    r[7] = p.x * (bf2f((unsigned short)y0[7]) + b01.w) + p.y * (bf2f((unsigned short)y1[7]) + b11.w);
    float* op = out + (size_t)token * DM + cbase;
    *(float4*)op       = make_float4(r[0], r[1], r[2], r[3]);
    *(float4*)(op + 4) = make_float4(r[4], r[5], r[6], r[7]);
}

// ---------------- launch ----------------
extern "C" void kernel_launch(void* const* d_in, const int* in_sizes, int n_in,
                              void* d_out, int out_size, void* d_ws, size_t ws_size,
                              hipStream_t stream) {
    const float* x       = (const float*)d_in[0];
    const int*   task_id = (const int*)d_in[1];
    const float* w1      = (const float*)d_in[2];
    const float* b1      = (const float*)d_in[3];
    const float* w2      = (const float*)d_in[4];
    const float* b2      = (const float*)d_in[5];
    const float* temb    = (const float*)d_in[6];
    const float* gw      = (const float*)d_in[7];
    const float* gb      = (const float*)d_in[8];
    float* out = (float*)d_out;

    char* ws = (char*)d_ws;
    double* bstats   = (double*)(ws + WS_BSTATS);
    double* dmean    = (double*)(ws + WS_DMEAN);
    double* drstd    = (double*)(ws + WS_DRSTD);
    double* dcolsum  = (double*)(ws + WS_DCOLSUM);
    double* dtask    = (double*)(ws + WS_DTASK);
    int*    hist     = (int*)(ws + WS_HIST);
    int*    cursor   = (int*)(ws + WS_CURSOR);
    int*    seg_off  = (int*)(ws + WS_SEGOFF);
    int2*   route_e  = (int2*)(ws + WS_ROUTE_E);
    float2* route_p  = (float2*)(ws + WS_ROUTE_P);
    int*    atok     = (int*)(ws + WS_ATOK);
    float*  aprob    = (float*)(ws + WS_APROB);
    int*    tokpos   = (int*)(ws + WS_TOKPOS);
    unsigned short* w1t = (unsigned short*)(ws + WS_W1T);
    unsigned short* w2t = (unsigned short*)(ws + WS_W2T);
    unsigned short* xb  = (unsigned short*)(ws + WS_XB);
    unsigned short* Y   = (unsigned short*)(ws + WS_Y);
    unsigned short* H   = (unsigned short*)(ws + WS_H);

    // M-chunk size (tiles): as large as ws allows (occupancy > cache residency)
    int TPC = (int)((ws_size - (size_t)WS_H) / (size_t)(128 * DFF * 2));
    if (TPC > MAXTILES) TPC = MAXTILES;
    TPC &= ~1;
    if (TPC < 2) TPC = 2;

    // ws header zero; -1 fill assignment list (pad rows). (d_out final region fully
    // written by k_combine; lb/topk/task by their kernels -> no d_out memset needed)
    hipMemsetAsync(ws, 0, WS_HDR_END, stream);
    hipMemsetAsync(ws + WS_ATOK, 0xFF, (size_t)MAXROWS * sizeof(int), stream);

    // weight transpose + bf16 convert + x copy
    k_transpose_bf16<<<dim3(DFF / 32, DM / 32, NE), 256, 0, stream>>>(w1, w1t, DM, DFF);
    k_transpose_bf16<<<dim3(DM / 32, DFF / 32, NE), 256, 0, stream>>>(w2, w2t, DFF, DM);
    k_xbf16<<<NTOK * DM / 8 / 256, 256, 0, stream>>>(x, xb);

    // layernorm stats
    k_reduce_stats<<<dim3(64, NB), 256, 0, stream>>>(x, bstats);
    k_finalize<<<1, 256, 0, stream>>>(bstats, dmean, drstd, dcolsum, dtask,
                                      gw, gb, temb, task_id, out + OUT_TASK);

    // gate + routing
    k_gate<<<NTOK / 256, 256, 0, stream>>>(x, gw, dmean, drstd, dcolsum, dtask,
                                           hist, route_e, route_p, out + OUT_TOPK);
    k_offsets_lb<<<1, 64, 0, stream>>>(hist, seg_off, out + OUT_LB);
    k_scatter<<<NTOK / 256, 256, 0, stream>>>(route_e, route_p, seg_off, cursor,
                                              atok, aprob, tokpos);

    // expert GEMMs, chunked over assignment rows
    for (int t0 = 0; t0 < MAXTILES; t0 += TPC) {
        k_gemm1<<<TPC * 16, 256, 0, stream>>>(xb, w1t, b1, atok, seg_off, H, t0);
        k_gemm2<<<TPC * 4, 256, 0, stream>>>(H, w2t, seg_off, Y, t0);
    }
    k_combine<<<NTOK / 4, 256, 0, stream>>>(Y, b2, tokpos, route_e, route_p, out);
}